// Round 9
// baseline (115.156 us; speedup 1.0000x reference)
//
#include <hip/hip_runtime.h>

// NeighbourCovariance: V=200000, C=3, F=16, K=32
// out[v] = [cov_flat (F*6=96), mean_flat (F*3=48)] -> 144 f32 per vertex.
//
// Ledger:
//  R3: NT stores -> 3x write amplification. BANNED.
//  R4: f32 coord packing neutral; VGPRs cost occupancy.
//  R5: fp16 gather: FETCH 540->333 MB, 131 us.
//  R6: u8 feats (scale cancels): FETCH 333->186 MB, 115 us.
//  R7: fused 24B record: FETCH 186->147 MB, 98 us. No pipe saturated.
//  R8: BATCH=16 alone: DEFEATED by compiler re-fusion (VGPR stuck at 48 ->
//      only ~2 gathers in flight). Latency-bound diagnosis stands untested.
//  R9: force the batch with sched_barrier(0) between load and compute
//      loops. 32 loads in flight/wave. VGPR ~100 -> still 4 waves/SIMD.

#define EPS 1e-6f

constexpr int C_DIM = 3;
constexpr int F_DIM = 16;
constexpr int K_N = 32;
constexpr int V_PER_BLOCK = 64;   // 256 threads, 4 threads/vertex
constexpr int THREADS = 256;
constexpr int BATCH = 16;         // gathers in flight per thread (forced)

typedef float v4f __attribute__((ext_vector_type(4)));
typedef _Float16 h4 __attribute__((ext_vector_type(4)));   // 8B
typedef unsigned int u32;

// Record: dwords [0..3] = 16 u8 feats, dwords [4..5] = fp16 x,y,z + pad.
// Stride 6 dwords = 24B; 8B-aligned for every v.

// ---------------------------------------------------------------------------
// Prepass: build rec[V] from f32 inputs.
// ---------------------------------------------------------------------------
__global__ __launch_bounds__(256) void pack_rec_kernel(
    const float* __restrict__ coords,
    const float* __restrict__ feats,
    u32* __restrict__ rec,
    int V)
{
  int v = blockIdx.x * blockDim.x + threadIdx.x;
  if (v >= V) return;

  u32 r[6];
  #pragma unroll
  for (int q = 0; q < 4; ++q) {
    const v4f f = *reinterpret_cast<const v4f*>(feats + (size_t)v * F_DIM + q * 4);
    u32 b0 = (u32)__float2int_rn(fminf(fmaxf(f.x, 0.f), 1.f) * 255.f);
    u32 b1 = (u32)__float2int_rn(fminf(fmaxf(f.y, 0.f), 1.f) * 255.f);
    u32 b2 = (u32)__float2int_rn(fminf(fmaxf(f.z, 0.f), 1.f) * 255.f);
    u32 b3 = (u32)__float2int_rn(fminf(fmaxf(f.w, 0.f), 1.f) * 255.f);
    r[q] = b0 | (b1 << 8) | (b2 << 16) | (b3 << 24);
  }
  h4 c;
  c.x = (_Float16)coords[(size_t)v * 3 + 0];
  c.y = (_Float16)coords[(size_t)v * 3 + 1];
  c.z = (_Float16)coords[(size_t)v * 3 + 2];
  c.w = (_Float16)0.f;
  const u32* cw = reinterpret_cast<const u32*>(&c);
  r[4] = cw[0];
  r[5] = cw[1];

  u32* dst = rec + (size_t)v * 6;
  *reinterpret_cast<uint2*>(dst + 0) = make_uint2(r[0], r[1]);
  *reinterpret_cast<uint2*>(dst + 2) = make_uint2(r[2], r[3]);
  *reinterpret_cast<uint2*>(dst + 4) = make_uint2(r[4], r[5]);
}

// ---------------------------------------------------------------------------
// Main kernel (fused-record gather, FORCED 32 loads in flight).
// ---------------------------------------------------------------------------
__global__ __launch_bounds__(THREADS) void neigh_cov_r_kernel(
    const u32* __restrict__ rec,    // [V*6]
    const int* __restrict__ nidx,   // [V,32]
    float* __restrict__ out,        // [V,144]
    int V)
{
  __shared__ int sidx[V_PER_BLOCK][K_N + 1];   // stride 33: conflict-free

  const int tid = threadIdx.x;
  const int block_v0 = blockIdx.x * V_PER_BLOCK;

  {
    const long long base = (long long)block_v0 * K_N;
    const long long avail = (long long)V * K_N - base;
    #pragma unroll
    for (int i = tid; i < V_PER_BLOCK * K_N; i += THREADS) {
      int val = (i < avail) ? __builtin_nontemporal_load(nidx + base + i) : 0;
      sidx[i / K_N][i % K_N] = val;
    }
  }
  __syncthreads();

  const int vloc = tid >> 2;   // vertex within block
  const int t    = tid & 3;    // feature quad: features 4t..4t+3
  const int v    = block_v0 + vloc;
  if (v >= V) return;

  float s[4]   = {0.f, 0.f, 0.f, 0.f};
  float wx0[4] = {0.f, 0.f, 0.f, 0.f};
  float wx1[4] = {0.f, 0.f, 0.f, 0.f};
  float wx2[4] = {0.f, 0.f, 0.f, 0.f};
  float e00[4] = {0.f, 0.f, 0.f, 0.f};
  float e10[4] = {0.f, 0.f, 0.f, 0.f};
  float e11[4] = {0.f, 0.f, 0.f, 0.f};
  float e20[4] = {0.f, 0.f, 0.f, 0.f};
  float e21[4] = {0.f, 0.f, 0.f, 0.f};
  float e22[4] = {0.f, 0.f, 0.f, 0.f};

  #pragma unroll
  for (int kb = 0; kb < K_N; kb += BATCH) {
    u32 uq[BATCH];
    h4 cc[BATCH];
    #pragma unroll
    for (int u = 0; u < BATCH; ++u) {
      const int idx = sidx[vloc][kb + u];
      const u32* rp = rec + (size_t)idx * 6;
      uq[u] = rp[t];                                  // feature word (lane t)
      cc[u] = *reinterpret_cast<const h4*>(rp + 4);   // coords, 8B-aligned
    }
    // Pin the schedule: all BATCH*2 loads must be issued before any compute
    // below moves up (R8: without this the scheduler re-fuses to ~2 in
    // flight). s_waitcnt for each use is still inserted by the compiler.
    __builtin_amdgcn_sched_barrier(0);
    #pragma unroll
    for (int u = 0; u < BATCH; ++u) {
      const float x0 = (float)cc[u].x;
      const float x1 = (float)cc[u].y;
      const float x2 = (float)cc[u].z;
      const float xx00 = x0 * x0;
      const float xx10 = x1 * x0;
      const float xx11 = x1 * x1;
      const float xx20 = x2 * x0;
      const float xx21 = x2 * x1;
      const float xx22 = x2 * x2;
      const u32 q = uq[u];
      // v_cvt_f32_ubyte0..3
      const float wv[4] = {(float)(q & 0xffu), (float)((q >> 8) & 0xffu),
                           (float)((q >> 16) & 0xffu), (float)(q >> 24)};
      #pragma unroll
      for (int j = 0; j < 4; ++j) {
        const float w = wv[j];
        s[j]   += w;
        wx0[j] = fmaf(w, x0, wx0[j]);
        wx1[j] = fmaf(w, x1, wx1[j]);
        wx2[j] = fmaf(w, x2, wx2[j]);
        e00[j] = fmaf(w, xx00, e00[j]);
        e10[j] = fmaf(w, xx10, e10[j]);
        e11[j] = fmaf(w, xx11, e11[j]);
        e20[j] = fmaf(w, xx20, e20[j]);
        e21[j] = fmaf(w, xx21, e21[j]);
        e22[j] = fmaf(w, xx22, e22[j]);
      }
    }
  }

  // Epilogue. Raw counts: s = 255*wsum; iw scale cancels with EPS*255.
  float cov[24];
  float mn[12];
  #pragma unroll
  for (int j = 0; j < 4; ++j) {
    const float iw = 1.0f / (s[j] + 255.0f * EPS);
    const float m0 = wx0[j] * iw;
    const float m1 = wx1[j] * iw;
    const float m2 = wx2[j] * iw;
    cov[j * 6 + 0] = fmaf(-m0, m0, e00[j] * iw);
    cov[j * 6 + 1] = fmaf(-m1, m0, e10[j] * iw);
    cov[j * 6 + 2] = fmaf(-m1, m1, e11[j] * iw);
    cov[j * 6 + 3] = fmaf(-m2, m0, e20[j] * iw);
    cov[j * 6 + 4] = fmaf(-m2, m1, e21[j] * iw);
    cov[j * 6 + 5] = fmaf(-m2, m2, e22[j] * iw);
    mn[j * 3 + 0] = m0;
    mn[j * 3 + 1] = m1;
    mn[j * 3 + 2] = m2;
  }

  // Normal cached float4 stores (L2 write-combines). All 16B-aligned.
  float* outv = out + (size_t)v * 144;
  v4f* cdst = reinterpret_cast<v4f*>(outv + t * 24);       // 24 floats
  const v4f* csrc = reinterpret_cast<const v4f*>(cov);
  #pragma unroll
  for (int q = 0; q < 6; ++q) cdst[q] = csrc[q];
  v4f* mdst = reinterpret_cast<v4f*>(outv + 96 + t * 12);  // 12 floats
  const v4f* msrc = reinterpret_cast<const v4f*>(mn);
  #pragma unroll
  for (int q = 0; q < 3; ++q) mdst[q] = msrc[q];
}

// ---------------------------------------------------------------------------
// Fallback (no workspace): f32 path, R1 structure.
// ---------------------------------------------------------------------------
__global__ __launch_bounds__(THREADS) void neigh_cov_f_kernel(
    const float* __restrict__ coords,
    const float* __restrict__ feats,
    const int*   __restrict__ nidx,
    float*       __restrict__ out,
    int V)
{
  __shared__ int sidx[V_PER_BLOCK][K_N + 1];
  const int tid = threadIdx.x;
  const int block_v0 = blockIdx.x * V_PER_BLOCK;
  {
    const long long base = (long long)block_v0 * K_N;
    const long long avail = (long long)V * K_N - base;
    for (int i = tid; i < V_PER_BLOCK * K_N; i += THREADS) {
      int val = (i < avail) ? nidx[base + i] : 0;
      sidx[i / K_N][i % K_N] = val;
    }
  }
  __syncthreads();
  const int vloc = tid >> 2, t = tid & 3;
  const int v = block_v0 + vloc;
  if (v >= V) return;
  float s[4] = {0,0,0,0}, wx0[4] = {0,0,0,0}, wx1[4] = {0,0,0,0}, wx2[4] = {0,0,0,0};
  float e00[4] = {0,0,0,0}, e10[4] = {0,0,0,0}, e11[4] = {0,0,0,0};
  float e20[4] = {0,0,0,0}, e21[4] = {0,0,0,0}, e22[4] = {0,0,0,0};
  #pragma unroll 4
  for (int k = 0; k < K_N; ++k) {
    const int idx = sidx[vloc][k];
    const v4f w4 = *reinterpret_cast<const v4f*>(feats + (size_t)idx * F_DIM + t * 4);
    const float x0 = coords[(size_t)idx * C_DIM + 0];
    const float x1 = coords[(size_t)idx * C_DIM + 1];
    const float x2 = coords[(size_t)idx * C_DIM + 2];
    const float xx00 = x0*x0, xx10 = x1*x0, xx11 = x1*x1;
    const float xx20 = x2*x0, xx21 = x2*x1, xx22 = x2*x2;
    const float wv[4] = {w4.x, w4.y, w4.z, w4.w};
    #pragma unroll
    for (int j = 0; j < 4; ++j) {
      const float w = wv[j];
      s[j] += w;
      wx0[j] = fmaf(w, x0, wx0[j]); wx1[j] = fmaf(w, x1, wx1[j]); wx2[j] = fmaf(w, x2, wx2[j]);
      e00[j] = fmaf(w, xx00, e00[j]); e10[j] = fmaf(w, xx10, e10[j]); e11[j] = fmaf(w, xx11, e11[j]);
      e20[j] = fmaf(w, xx20, e20[j]); e21[j] = fmaf(w, xx21, e21[j]); e22[j] = fmaf(w, xx22, e22[j]);
    }
  }
  float cov[24], mn[12];
  #pragma unroll
  for (int j = 0; j < 4; ++j) {
    const float iw = 1.0f / (s[j] + EPS);
    const float m0 = wx0[j]*iw, m1 = wx1[j]*iw, m2 = wx2[j]*iw;
    cov[j*6+0] = fmaf(-m0, m0, e00[j]*iw);
    cov[j*6+1] = fmaf(-m1, m0, e10[j]*iw);
    cov[j*6+2] = fmaf(-m1, m1, e11[j]*iw);
    cov[j*6+3] = fmaf(-m2, m0, e20[j]*iw);
    cov[j*6+4] = fmaf(-m2, m1, e21[j]*iw);
    cov[j*6+5] = fmaf(-m2, m2, e22[j]*iw);
    mn[j*3+0] = m0; mn[j*3+1] = m1; mn[j*3+2] = m2;
  }
  float* outv = out + (size_t)v * 144;
  v4f* cdst = reinterpret_cast<v4f*>(outv + t * 24);
  const v4f* csrc = reinterpret_cast<const v4f*>(cov);
  #pragma unroll
  for (int q = 0; q < 6; ++q) cdst[q] = csrc[q];
  v4f* mdst = reinterpret_cast<v4f*>(outv + 96 + t * 12);
  const v4f* msrc = reinterpret_cast<const v4f*>(mn);
  #pragma unroll
  for (int q = 0; q < 3; ++q) mdst[q] = msrc[q];
}

extern "C" void kernel_launch(void* const* d_in, const int* in_sizes, int n_in,
                              void* d_out, int out_size, void* d_ws, size_t ws_size,
                              hipStream_t stream) {
  const float* coords = (const float*)d_in[0];
  const float* feats  = (const float*)d_in[1];
  const int*   nidx   = (const int*)d_in[2];
  float* out = (float*)d_out;

  const int V = in_sizes[0] / C_DIM;   // 200000
  const int blocks = (V + V_PER_BLOCK - 1) / V_PER_BLOCK;

  const size_t rec_bytes = (size_t)V * 24;   // 4.8 MB
  const bool use_rec = (d_ws != nullptr) && (ws_size >= rec_bytes);

  if (use_rec) {
    u32* rec = (u32*)d_ws;
    pack_rec_kernel<<<(V + 255) / 256, 256, 0, stream>>>(coords, feats, rec, V);
    neigh_cov_r_kernel<<<blocks, THREADS, 0, stream>>>(rec, nidx, out, V);
  } else {
    neigh_cov_f_kernel<<<blocks, THREADS, 0, stream>>>(coords, feats, nidx, out, V);
  }
}

// Round 10
// 106.601 us; speedup vs baseline: 1.0803x; 1.0803x over previous
//
#include <hip/hip_runtime.h>

// NeighbourCovariance: V=200000, C=3, F=16, K=32
// out[v] = [cov_flat (F*6=96), mean_flat (F*3=48)] -> 144 f32 per vertex.
//
// Ledger:
//  R3: NT stores -> 3x write amplification. BANNED.
//  R4: f32 coord packing neutral; VGPRs cost occupancy.
//  R5: fp16 gather: FETCH 540->333 MB, 131 us.
//  R6: u8 feats (scale cancels): FETCH 333->186 MB, 115 us.
//  R7: fused 24B record: FETCH 186->147 MB, 98 us.
//  R8: BATCH=16 w/o pinning: compiler re-fused, flat. R9: pinned 32-deep
//      batch: VGPR 96, occ 19%, 109 us -> NOT latency-bound; behaves
//      line-fill-rate bound (time ~ lines touched/neighbor).
//  R10: 32B record (stride 8 dw): never straddles a 64B line; coord load
//       always L1-hits the same line. 1.0 fills/neighbor (was ~1.25-1.375).
//       Table 6.4MB > L2 -> FETCH rises a bit; fill work drops 25%.

#define EPS 1e-6f

constexpr int C_DIM = 3;
constexpr int F_DIM = 16;
constexpr int K_N = 32;
constexpr int V_PER_BLOCK = 64;   // 256 threads, 4 threads/vertex
constexpr int THREADS = 256;
constexpr int BATCH = 8;          // R7's best
constexpr int REC_DW = 8;         // 32B record stride in dwords

typedef float v4f __attribute__((ext_vector_type(4)));
typedef _Float16 h4 __attribute__((ext_vector_type(4)));   // 8B
typedef unsigned int u32;

// Record (32B, one cache line): dw[0..3] = 16 u8 feats, dw[4..5] = fp16
// x,y,z + pad, dw[6..7] = pad.

// ---------------------------------------------------------------------------
// Prepass: build rec[V] from f32 inputs.
// ---------------------------------------------------------------------------
__global__ __launch_bounds__(256) void pack_rec_kernel(
    const float* __restrict__ coords,
    const float* __restrict__ feats,
    u32* __restrict__ rec,
    int V)
{
  int v = blockIdx.x * blockDim.x + threadIdx.x;
  if (v >= V) return;

  u32 r[6];
  #pragma unroll
  for (int q = 0; q < 4; ++q) {
    const v4f f = *reinterpret_cast<const v4f*>(feats + (size_t)v * F_DIM + q * 4);
    u32 b0 = (u32)__float2int_rn(fminf(fmaxf(f.x, 0.f), 1.f) * 255.f);
    u32 b1 = (u32)__float2int_rn(fminf(fmaxf(f.y, 0.f), 1.f) * 255.f);
    u32 b2 = (u32)__float2int_rn(fminf(fmaxf(f.z, 0.f), 1.f) * 255.f);
    u32 b3 = (u32)__float2int_rn(fminf(fmaxf(f.w, 0.f), 1.f) * 255.f);
    r[q] = b0 | (b1 << 8) | (b2 << 16) | (b3 << 24);
  }
  h4 c;
  c.x = (_Float16)coords[(size_t)v * 3 + 0];
  c.y = (_Float16)coords[(size_t)v * 3 + 1];
  c.z = (_Float16)coords[(size_t)v * 3 + 2];
  c.w = (_Float16)0.f;
  const u32* cw = reinterpret_cast<const u32*>(&c);

  u32* dst = rec + (size_t)v * REC_DW;
  // Two 16B stores (16B-aligned since REC_DW=8).
  uint4 lo = make_uint4(r[0], r[1], r[2], r[3]);
  uint4 hi = make_uint4(cw[0], cw[1], 0u, 0u);
  *reinterpret_cast<uint4*>(dst + 0) = lo;
  *reinterpret_cast<uint4*>(dst + 4) = hi;
}

// ---------------------------------------------------------------------------
// Main kernel (fused 32B-record gather).
// ---------------------------------------------------------------------------
__global__ __launch_bounds__(THREADS) void neigh_cov_r_kernel(
    const u32* __restrict__ rec,    // [V*8]
    const int* __restrict__ nidx,   // [V,32]
    float* __restrict__ out,        // [V,144]
    int V)
{
  __shared__ int sidx[V_PER_BLOCK][K_N + 1];   // stride 33: conflict-free

  const int tid = threadIdx.x;
  const int block_v0 = blockIdx.x * V_PER_BLOCK;

  {
    const long long base = (long long)block_v0 * K_N;
    const long long avail = (long long)V * K_N - base;
    #pragma unroll
    for (int i = tid; i < V_PER_BLOCK * K_N; i += THREADS) {
      int val = (i < avail) ? __builtin_nontemporal_load(nidx + base + i) : 0;
      sidx[i / K_N][i % K_N] = val;
    }
  }
  __syncthreads();

  const int vloc = tid >> 2;   // vertex within block
  const int t    = tid & 3;    // feature quad: features 4t..4t+3
  const int v    = block_v0 + vloc;
  if (v >= V) return;

  float s[4]   = {0.f, 0.f, 0.f, 0.f};
  float wx0[4] = {0.f, 0.f, 0.f, 0.f};
  float wx1[4] = {0.f, 0.f, 0.f, 0.f};
  float wx2[4] = {0.f, 0.f, 0.f, 0.f};
  float e00[4] = {0.f, 0.f, 0.f, 0.f};
  float e10[4] = {0.f, 0.f, 0.f, 0.f};
  float e11[4] = {0.f, 0.f, 0.f, 0.f};
  float e20[4] = {0.f, 0.f, 0.f, 0.f};
  float e21[4] = {0.f, 0.f, 0.f, 0.f};
  float e22[4] = {0.f, 0.f, 0.f, 0.f};

  #pragma unroll
  for (int kb = 0; kb < K_N; kb += BATCH) {
    u32 uq[BATCH];
    h4 cc[BATCH];
    #pragma unroll
    for (int u = 0; u < BATCH; ++u) {
      const int idx = sidx[vloc][kb + u];
      const u32* rp = rec + (size_t)idx * REC_DW;
      uq[u] = rp[t];                                  // feature word (lane t)
      cc[u] = *reinterpret_cast<const h4*>(rp + 4);   // coords, same line
    }
    #pragma unroll
    for (int u = 0; u < BATCH; ++u) {
      const float x0 = (float)cc[u].x;
      const float x1 = (float)cc[u].y;
      const float x2 = (float)cc[u].z;
      const float xx00 = x0 * x0;
      const float xx10 = x1 * x0;
      const float xx11 = x1 * x1;
      const float xx20 = x2 * x0;
      const float xx21 = x2 * x1;
      const float xx22 = x2 * x2;
      const u32 q = uq[u];
      // v_cvt_f32_ubyte0..3
      const float wv[4] = {(float)(q & 0xffu), (float)((q >> 8) & 0xffu),
                           (float)((q >> 16) & 0xffu), (float)(q >> 24)};
      #pragma unroll
      for (int j = 0; j < 4; ++j) {
        const float w = wv[j];
        s[j]   += w;
        wx0[j] = fmaf(w, x0, wx0[j]);
        wx1[j] = fmaf(w, x1, wx1[j]);
        wx2[j] = fmaf(w, x2, wx2[j]);
        e00[j] = fmaf(w, xx00, e00[j]);
        e10[j] = fmaf(w, xx10, e10[j]);
        e11[j] = fmaf(w, xx11, e11[j]);
        e20[j] = fmaf(w, xx20, e20[j]);
        e21[j] = fmaf(w, xx21, e21[j]);
        e22[j] = fmaf(w, xx22, e22[j]);
      }
    }
  }

  // Epilogue. Raw counts: s = 255*wsum; iw scale cancels with EPS*255.
  float cov[24];
  float mn[12];
  #pragma unroll
  for (int j = 0; j < 4; ++j) {
    const float iw = 1.0f / (s[j] + 255.0f * EPS);
    const float m0 = wx0[j] * iw;
    const float m1 = wx1[j] * iw;
    const float m2 = wx2[j] * iw;
    cov[j * 6 + 0] = fmaf(-m0, m0, e00[j] * iw);
    cov[j * 6 + 1] = fmaf(-m1, m0, e10[j] * iw);
    cov[j * 6 + 2] = fmaf(-m1, m1, e11[j] * iw);
    cov[j * 6 + 3] = fmaf(-m2, m0, e20[j] * iw);
    cov[j * 6 + 4] = fmaf(-m2, m1, e21[j] * iw);
    cov[j * 6 + 5] = fmaf(-m2, m2, e22[j] * iw);
    mn[j * 3 + 0] = m0;
    mn[j * 3 + 1] = m1;
    mn[j * 3 + 2] = m2;
  }

  // Normal cached float4 stores (L2 write-combines). All 16B-aligned.
  float* outv = out + (size_t)v * 144;
  v4f* cdst = reinterpret_cast<v4f*>(outv + t * 24);       // 24 floats
  const v4f* csrc = reinterpret_cast<const v4f*>(cov);
  #pragma unroll
  for (int q = 0; q < 6; ++q) cdst[q] = csrc[q];
  v4f* mdst = reinterpret_cast<v4f*>(outv + 96 + t * 12);  // 12 floats
  const v4f* msrc = reinterpret_cast<const v4f*>(mn);
  #pragma unroll
  for (int q = 0; q < 3; ++q) mdst[q] = msrc[q];
}

// ---------------------------------------------------------------------------
// Fallback (no workspace): f32 path, R1 structure.
// ---------------------------------------------------------------------------
__global__ __launch_bounds__(THREADS) void neigh_cov_f_kernel(
    const float* __restrict__ coords,
    const float* __restrict__ feats,
    const int*   __restrict__ nidx,
    float*       __restrict__ out,
    int V)
{
  __shared__ int sidx[V_PER_BLOCK][K_N + 1];
  const int tid = threadIdx.x;
  const int block_v0 = blockIdx.x * V_PER_BLOCK;
  {
    const long long base = (long long)block_v0 * K_N;
    const long long avail = (long long)V * K_N - base;
    for (int i = tid; i < V_PER_BLOCK * K_N; i += THREADS) {
      int val = (i < avail) ? nidx[base + i] : 0;
      sidx[i / K_N][i % K_N] = val;
    }
  }
  __syncthreads();
  const int vloc = tid >> 2, t = tid & 3;
  const int v = block_v0 + vloc;
  if (v >= V) return;
  float s[4] = {0,0,0,0}, wx0[4] = {0,0,0,0}, wx1[4] = {0,0,0,0}, wx2[4] = {0,0,0,0};
  float e00[4] = {0,0,0,0}, e10[4] = {0,0,0,0}, e11[4] = {0,0,0,0};
  float e20[4] = {0,0,0,0}, e21[4] = {0,0,0,0}, e22[4] = {0,0,0,0};
  #pragma unroll 4
  for (int k = 0; k < K_N; ++k) {
    const int idx = sidx[vloc][k];
    const v4f w4 = *reinterpret_cast<const v4f*>(feats + (size_t)idx * F_DIM + t * 4);
    const float x0 = coords[(size_t)idx * C_DIM + 0];
    const float x1 = coords[(size_t)idx * C_DIM + 1];
    const float x2 = coords[(size_t)idx * C_DIM + 2];
    const float xx00 = x0*x0, xx10 = x1*x0, xx11 = x1*x1;
    const float xx20 = x2*x0, xx21 = x2*x1, xx22 = x2*x2;
    const float wv[4] = {w4.x, w4.y, w4.z, w4.w};
    #pragma unroll
    for (int j = 0; j < 4; ++j) {
      const float w = wv[j];
      s[j] += w;
      wx0[j] = fmaf(w, x0, wx0[j]); wx1[j] = fmaf(w, x1, wx1[j]); wx2[j] = fmaf(w, x2, wx2[j]);
      e00[j] = fmaf(w, xx00, e00[j]); e10[j] = fmaf(w, xx10, e10[j]); e11[j] = fmaf(w, xx11, e11[j]);
      e20[j] = fmaf(w, xx20, e20[j]); e21[j] = fmaf(w, xx21, e21[j]); e22[j] = fmaf(w, xx22, e22[j]);
    }
  }
  float cov[24], mn[12];
  #pragma unroll
  for (int j = 0; j < 4; ++j) {
    const float iw = 1.0f / (s[j] + EPS);
    const float m0 = wx0[j]*iw, m1 = wx1[j]*iw, m2 = wx2[j]*iw;
    cov[j*6+0] = fmaf(-m0, m0, e00[j]*iw);
    cov[j*6+1] = fmaf(-m1, m0, e10[j]*iw);
    cov[j*6+2] = fmaf(-m1, m1, e11[j]*iw);
    cov[j*6+3] = fmaf(-m2, m0, e20[j]*iw);
    cov[j*6+4] = fmaf(-m2, m1, e21[j]*iw);
    cov[j*6+5] = fmaf(-m2, m2, e22[j]*iw);
    mn[j*3+0] = m0; mn[j*3+1] = m1; mn[j*3+2] = m2;
  }
  float* outv = out + (size_t)v * 144;
  v4f* cdst = reinterpret_cast<v4f*>(outv + t * 24);
  const v4f* csrc = reinterpret_cast<const v4f*>(cov);
  #pragma unroll
  for (int q = 0; q < 6; ++q) cdst[q] = csrc[q];
  v4f* mdst = reinterpret_cast<v4f*>(outv + 96 + t * 12);
  const v4f* msrc = reinterpret_cast<const v4f*>(mn);
  #pragma unroll
  for (int q = 0; q < 3; ++q) mdst[q] = msrc[q];
}

extern "C" void kernel_launch(void* const* d_in, const int* in_sizes, int n_in,
                              void* d_out, int out_size, void* d_ws, size_t ws_size,
                              hipStream_t stream) {
  const float* coords = (const float*)d_in[0];
  const float* feats  = (const float*)d_in[1];
  const int*   nidx   = (const int*)d_in[2];
  float* out = (float*)d_out;

  const int V = in_sizes[0] / C_DIM;   // 200000
  const int blocks = (V + V_PER_BLOCK - 1) / V_PER_BLOCK;

  const size_t rec_bytes = (size_t)V * REC_DW * 4;   // 6.4 MB
  const bool use_rec = (d_ws != nullptr) && (ws_size >= rec_bytes);

  if (use_rec) {
    u32* rec = (u32*)d_ws;
    pack_rec_kernel<<<(V + 255) / 256, 256, 0, stream>>>(coords, feats, rec, V);
    neigh_cov_r_kernel<<<blocks, THREADS, 0, stream>>>(rec, nidx, out, V);
  } else {
    neigh_cov_f_kernel<<<blocks, THREADS, 0, stream>>>(coords, feats, nidx, out, V);
  }
}

// Round 12
// 99.176 us; speedup vs baseline: 1.1611x; 1.0749x over previous
//
#include <hip/hip_runtime.h>

// NeighbourCovariance: V=200000, C=3, F=16, K=32
// out[v] = [cov_flat (F*6=96), mean_flat (F*3=48)] -> 144 f32 per vertex.
//
// Ledger:
//  R3: NT stores -> 3x write amplification. BANNED.
//  R4: f32 coord packing neutral.
//  R5: fp16 gather: FETCH 540->333 MB, 131 us.
//  R6: u8 feats: FETCH 333->186 MB, 115 us (2 line-touches/neighbor).
//  R7: fused 24B record: 147 MB, 98 us (~1.25 touches/neighbor).
//  R8/R9: MLP 2->32 deep, occ 44->19%: FLAT. Not latency-bound.
//  R10: 32B record: FETCH +54MB, time FLAT -> fetch bytes free; invariant
//       is ACCESSES per neighbor (2). Theory: L1/TA access-rate wall.
//  R11: one-dwordx4 layout, but half/word selectors SWAPPED (lane1<->lane2
//       got each other's quads) -> absmax 1.67. Fixed in R12:
//       half_off=(t>>1)*4, word=(t&1). q0,q1 in lo half; q2,q3 in hi.

#define EPS 1e-6f

constexpr int C_DIM = 3;
constexpr int F_DIM = 16;
constexpr int K_N = 32;
constexpr int V_PER_BLOCK = 64;   // 256 threads, 4 threads/vertex
constexpr int THREADS = 256;
constexpr int BATCH = 8;
constexpr int REC_DW = 8;         // 32B record

typedef float v4f __attribute__((ext_vector_type(4)));
typedef unsigned int u32;
typedef u32 v4u __attribute__((ext_vector_type(4)));
typedef _Float16 h2 __attribute__((ext_vector_type(2)));

static __device__ inline void unpack_h2(u32 u, float& a, float& b) {
  h2 hv = __builtin_bit_cast(h2, u);
  a = (float)hv.x;
  b = (float)hv.y;
}

// ---------------------------------------------------------------------------
// Prepass: build rec[V] (32B each): [q0, cxy, q1, cz, q2, cxy, q3, cz]
//   q_j  = features 4j..4j+3 as packed u8 (x255)
//   cxy  = fp16 x | fp16 y;   cz = fp16 z | 0   (duplicated in both halves)
// Lane t reads the 16B half (t>>1) and picks word (t&1) ? .z : .x as its
// feature quad; .y/.w are the coords in BOTH halves.
// ---------------------------------------------------------------------------
__global__ __launch_bounds__(256) void pack_rec_kernel(
    const float* __restrict__ coords,
    const float* __restrict__ feats,
    u32* __restrict__ rec,
    int V)
{
  int v = blockIdx.x * blockDim.x + threadIdx.x;
  if (v >= V) return;

  u32 q[4];
  #pragma unroll
  for (int i = 0; i < 4; ++i) {
    const v4f f = *reinterpret_cast<const v4f*>(feats + (size_t)v * F_DIM + i * 4);
    u32 b0 = (u32)__float2int_rn(fminf(fmaxf(f.x, 0.f), 1.f) * 255.f);
    u32 b1 = (u32)__float2int_rn(fminf(fmaxf(f.y, 0.f), 1.f) * 255.f);
    u32 b2 = (u32)__float2int_rn(fminf(fmaxf(f.z, 0.f), 1.f) * 255.f);
    u32 b3 = (u32)__float2int_rn(fminf(fmaxf(f.w, 0.f), 1.f) * 255.f);
    q[i] = b0 | (b1 << 8) | (b2 << 16) | (b3 << 24);
  }
  h2 cxy, cz;
  cxy.x = (_Float16)coords[(size_t)v * 3 + 0];
  cxy.y = (_Float16)coords[(size_t)v * 3 + 1];
  cz.x  = (_Float16)coords[(size_t)v * 3 + 2];
  cz.y  = (_Float16)0.f;
  const u32 uxy = __builtin_bit_cast(u32, cxy);
  const u32 uz  = __builtin_bit_cast(u32, cz);

  u32* dst = rec + (size_t)v * REC_DW;
  v4u lo, hi;
  lo.x = q[0]; lo.y = uxy; lo.z = q[1]; lo.w = uz;   // half 0: quads 0,1
  hi.x = q[2]; hi.y = uxy; hi.z = q[3]; hi.w = uz;   // half 1: quads 2,3
  *reinterpret_cast<v4u*>(dst + 0) = lo;
  *reinterpret_cast<v4u*>(dst + 4) = hi;
}

// ---------------------------------------------------------------------------
// Main kernel: ONE dwordx4 gather per neighbor per lane.
// ---------------------------------------------------------------------------
__global__ __launch_bounds__(THREADS) void neigh_cov_r_kernel(
    const u32* __restrict__ rec,    // [V*8]
    const int* __restrict__ nidx,   // [V,32]
    float* __restrict__ out,        // [V,144]
    int V)
{
  __shared__ int sidx[V_PER_BLOCK][K_N + 1];   // stride 33: conflict-free

  const int tid = threadIdx.x;
  const int block_v0 = blockIdx.x * V_PER_BLOCK;

  {
    const long long base = (long long)block_v0 * K_N;
    const long long avail = (long long)V * K_N - base;
    #pragma unroll
    for (int i = tid; i < V_PER_BLOCK * K_N; i += THREADS) {
      int val = (i < avail) ? __builtin_nontemporal_load(nidx + base + i) : 0;
      sidx[i / K_N][i % K_N] = val;
    }
  }
  __syncthreads();

  const int vloc = tid >> 2;        // vertex within block
  const int t    = tid & 3;         // feature quad owner
  const int v    = block_v0 + vloc;
  if (v >= V) return;

  const int half_off = (t >> 1) * 4;  // 16B half holding my quad (q0,q1|q2,q3)
  const bool hi_word = (t & 1);       // my feat word within the half: .x or .z

  float s[4]   = {0.f, 0.f, 0.f, 0.f};
  float wx0[4] = {0.f, 0.f, 0.f, 0.f};
  float wx1[4] = {0.f, 0.f, 0.f, 0.f};
  float wx2[4] = {0.f, 0.f, 0.f, 0.f};
  float e00[4] = {0.f, 0.f, 0.f, 0.f};
  float e10[4] = {0.f, 0.f, 0.f, 0.f};
  float e11[4] = {0.f, 0.f, 0.f, 0.f};
  float e20[4] = {0.f, 0.f, 0.f, 0.f};
  float e21[4] = {0.f, 0.f, 0.f, 0.f};
  float e22[4] = {0.f, 0.f, 0.f, 0.f};

  #pragma unroll
  for (int kb = 0; kb < K_N; kb += BATCH) {
    v4u r[BATCH];
    #pragma unroll
    for (int u = 0; u < BATCH; ++u) {
      const int idx = sidx[vloc][kb + u];
      r[u] = *reinterpret_cast<const v4u*>(rec + (size_t)idx * REC_DW + half_off);
    }
    #pragma unroll
    for (int u = 0; u < BATCH; ++u) {
      float x0, x1, x2, zpad;
      unpack_h2(r[u].y, x0, x1);
      unpack_h2(r[u].w, x2, zpad);
      const u32 q = hi_word ? r[u].z : r[u].x;

      const float xx00 = x0 * x0;
      const float xx10 = x1 * x0;
      const float xx11 = x1 * x1;
      const float xx20 = x2 * x0;
      const float xx21 = x2 * x1;
      const float xx22 = x2 * x2;
      // v_cvt_f32_ubyte0..3
      const float wv[4] = {(float)(q & 0xffu), (float)((q >> 8) & 0xffu),
                           (float)((q >> 16) & 0xffu), (float)(q >> 24)};
      #pragma unroll
      for (int j = 0; j < 4; ++j) {
        const float w = wv[j];
        s[j]   += w;
        wx0[j] = fmaf(w, x0, wx0[j]);
        wx1[j] = fmaf(w, x1, wx1[j]);
        wx2[j] = fmaf(w, x2, wx2[j]);
        e00[j] = fmaf(w, xx00, e00[j]);
        e10[j] = fmaf(w, xx10, e10[j]);
        e11[j] = fmaf(w, xx11, e11[j]);
        e20[j] = fmaf(w, xx20, e20[j]);
        e21[j] = fmaf(w, xx21, e21[j]);
        e22[j] = fmaf(w, xx22, e22[j]);
      }
    }
  }

  // Epilogue. Raw counts: s = 255*wsum; iw scale cancels with EPS*255.
  float cov[24];
  float mn[12];
  #pragma unroll
  for (int j = 0; j < 4; ++j) {
    const float iw = 1.0f / (s[j] + 255.0f * EPS);
    const float m0 = wx0[j] * iw;
    const float m1 = wx1[j] * iw;
    const float m2 = wx2[j] * iw;
    cov[j * 6 + 0] = fmaf(-m0, m0, e00[j] * iw);
    cov[j * 6 + 1] = fmaf(-m1, m0, e10[j] * iw);
    cov[j * 6 + 2] = fmaf(-m1, m1, e11[j] * iw);
    cov[j * 6 + 3] = fmaf(-m2, m0, e20[j] * iw);
    cov[j * 6 + 4] = fmaf(-m2, m1, e21[j] * iw);
    cov[j * 6 + 5] = fmaf(-m2, m2, e22[j] * iw);
    mn[j * 3 + 0] = m0;
    mn[j * 3 + 1] = m1;
    mn[j * 3 + 2] = m2;
  }

  // Normal cached float4 stores (L2 write-combines). All 16B-aligned.
  float* outv = out + (size_t)v * 144;
  v4f* cdst = reinterpret_cast<v4f*>(outv + t * 24);       // 24 floats
  const v4f* csrc = reinterpret_cast<const v4f*>(cov);
  #pragma unroll
  for (int q2 = 0; q2 < 6; ++q2) cdst[q2] = csrc[q2];
  v4f* mdst = reinterpret_cast<v4f*>(outv + 96 + t * 12);  // 12 floats
  const v4f* msrc = reinterpret_cast<const v4f*>(mn);
  #pragma unroll
  for (int q2 = 0; q2 < 3; ++q2) mdst[q2] = msrc[q2];
}

// ---------------------------------------------------------------------------
// Fallback (no workspace): f32 path, R1 structure.
// ---------------------------------------------------------------------------
__global__ __launch_bounds__(THREADS) void neigh_cov_f_kernel(
    const float* __restrict__ coords,
    const float* __restrict__ feats,
    const int*   __restrict__ nidx,
    float*       __restrict__ out,
    int V)
{
  __shared__ int sidx[V_PER_BLOCK][K_N + 1];
  const int tid = threadIdx.x;
  const int block_v0 = blockIdx.x * V_PER_BLOCK;
  {
    const long long base = (long long)block_v0 * K_N;
    const long long avail = (long long)V * K_N - base;
    for (int i = tid; i < V_PER_BLOCK * K_N; i += THREADS) {
      int val = (i < avail) ? nidx[base + i] : 0;
      sidx[i / K_N][i % K_N] = val;
    }
  }
  __syncthreads();
  const int vloc = tid >> 2, t = tid & 3;
  const int v = block_v0 + vloc;
  if (v >= V) return;
  float s[4] = {0,0,0,0}, wx0[4] = {0,0,0,0}, wx1[4] = {0,0,0,0}, wx2[4] = {0,0,0,0};
  float e00[4] = {0,0,0,0}, e10[4] = {0,0,0,0}, e11[4] = {0,0,0,0};
  float e20[4] = {0,0,0,0}, e21[4] = {0,0,0,0}, e22[4] = {0,0,0,0};
  #pragma unroll 4
  for (int k = 0; k < K_N; ++k) {
    const int idx = sidx[vloc][k];
    const v4f w4 = *reinterpret_cast<const v4f*>(feats + (size_t)idx * F_DIM + t * 4);
    const float x0 = coords[(size_t)idx * C_DIM + 0];
    const float x1 = coords[(size_t)idx * C_DIM + 1];
    const float x2 = coords[(size_t)idx * C_DIM + 2];
    const float xx00 = x0*x0, xx10 = x1*x0, xx11 = x1*x1;
    const float xx20 = x2*x0, xx21 = x2*x1, xx22 = x2*x2;
    const float wv[4] = {w4.x, w4.y, w4.z, w4.w};
    #pragma unroll
    for (int j = 0; j < 4; ++j) {
      const float w = wv[j];
      s[j] += w;
      wx0[j] = fmaf(w, x0, wx0[j]); wx1[j] = fmaf(w, x1, wx1[j]); wx2[j] = fmaf(w, x2, wx2[j]);
      e00[j] = fmaf(w, xx00, e00[j]); e10[j] = fmaf(w, xx10, e10[j]); e11[j] = fmaf(w, xx11, e11[j]);
      e20[j] = fmaf(w, xx20, e20[j]); e21[j] = fmaf(w, xx21, e21[j]); e22[j] = fmaf(w, xx22, e22[j]);
    }
  }
  float cov[24], mn[12];
  #pragma unroll
  for (int j = 0; j < 4; ++j) {
    const float iw = 1.0f / (s[j] + EPS);
    const float m0 = wx0[j]*iw, m1 = wx1[j]*iw, m2 = wx2[j]*iw;
    cov[j*6+0] = fmaf(-m0, m0, e00[j]*iw);
    cov[j*6+1] = fmaf(-m1, m0, e10[j]*iw);
    cov[j*6+2] = fmaf(-m1, m1, e11[j]*iw);
    cov[j*6+3] = fmaf(-m2, m0, e20[j]*iw);
    cov[j*6+4] = fmaf(-m2, m1, e21[j]*iw);
    cov[j*6+5] = fmaf(-m2, m2, e22[j]*iw);
    mn[j*3+0] = m0; mn[j*3+1] = m1; mn[j*3+2] = m2;
  }
  float* outv = out + (size_t)v * 144;
  v4f* cdst = reinterpret_cast<v4f*>(outv + t * 24);
  const v4f* csrc = reinterpret_cast<const v4f*>(cov);
  #pragma unroll
  for (int q = 0; q < 6; ++q) cdst[q] = csrc[q];
  v4f* mdst = reinterpret_cast<v4f*>(outv + 96 + t * 12);
  const v4f* msrc = reinterpret_cast<const v4f*>(mn);
  #pragma unroll
  for (int q = 0; q < 3; ++q) mdst[q] = msrc[q];
}

extern "C" void kernel_launch(void* const* d_in, const int* in_sizes, int n_in,
                              void* d_out, int out_size, void* d_ws, size_t ws_size,
                              hipStream_t stream) {
  const float* coords = (const float*)d_in[0];
  const float* feats  = (const float*)d_in[1];
  const int*   nidx   = (const int*)d_in[2];
  float* out = (float*)d_out;

  const int V = in_sizes[0] / C_DIM;   // 200000
  const int blocks = (V + V_PER_BLOCK - 1) / V_PER_BLOCK;

  const size_t rec_bytes = (size_t)V * REC_DW * 4;   // 6.4 MB
  const bool use_rec = (d_ws != nullptr) && (ws_size >= rec_bytes);

  if (use_rec) {
    u32* rec = (u32*)d_ws;
    pack_rec_kernel<<<(V + 255) / 256, 256, 0, stream>>>(coords, feats, rec, V);
    neigh_cov_r_kernel<<<blocks, THREADS, 0, stream>>>(rec, nidx, out, V);
  } else {
    neigh_cov_f_kernel<<<blocks, THREADS, 0, stream>>>(coords, feats, nidx, out, V);
  }
}